// Round 1
// baseline (1505.942 us; speedup 1.0000x reference)
//
#include <hip/hip_runtime.h>
#include <math.h>

// ---------------------------------------------------------------------------
// SGCN forward, fp32.
//   layer1: ap = seg_mean(x,pos); an = seg_mean(x,neg)
//           z  = tanh([ [ap,x]@W1p+b1p , [an,x]@W1n+b1n ])            (N,64)
//   layer2: Ap = seg_mean(z,pos) (64d); An = seg_mean(z,neg) (64d)
//           out_p = [Ap[:,0:32], An[:,32:64], z[:,0:32] ] @ W2p + b2p
//           out_n = [Ap[:,32:64], An[:,0:32], z[:,32:64]] @ W2n + b2n
//           out = tanh([out_p, out_n])                                 (N,64)
// ---------------------------------------------------------------------------

// One 64-lane wave per edge; lane k handles feature k. Handles pos edges in
// the first E waves and neg edges in the next E waves (wave-uniform branch).
__global__ void __launch_bounds__(256) scatter2(
    const float* __restrict__ feat,
    const int*   __restrict__ pos,   // [2*E] : src then dst
    const int*   __restrict__ neg,
    float* __restrict__ agg_p, float* __restrict__ agg_n,
    float* __restrict__ cnt_p, float* __restrict__ cnt_n,
    int E, int do_cnt)
{
    int t = blockIdx.x * 256 + threadIdx.x;
    int e = t >> 6;
    int k = t & 63;
    const int* sp; const int* dp; float* acc; float* cn;
    if (e < E) { sp = pos;  dp = pos + E; acc = agg_p; cn = cnt_p; }
    else       { e -= E; sp = neg; dp = neg + E; acc = agg_n; cn = cnt_n; }
    if (e >= E) return;
    int s = sp[e];
    int d = dp[e];
    float v = feat[s * 64 + k];                 // coalesced 256B per wave
    unsafeAtomicAdd(&acc[d * 64 + k], v);       // native global_atomic_add_f32
    if (do_cnt && k == 0) unsafeAtomicAdd(&cn[d], 1.0f);
}

// One wave per node. Lanes 0..31 compute out_p, lanes 32..63 compute out_n.
// W staged in LDS interleaved: W[j*64 + c] = (c<32) ? W1p[j][c] : W1n[j][c-32]
__global__ void __launch_bounds__(256) layer1_k(
    const float* __restrict__ x,
    const float* __restrict__ agg_p, const float* __restrict__ agg_n,
    const float* __restrict__ cnt_p, const float* __restrict__ cnt_n,
    const float* __restrict__ W1p, const float* __restrict__ b1p,
    const float* __restrict__ W1n, const float* __restrict__ b1n,
    float* __restrict__ z, int n)
{
    __shared__ float W[128 * 64];      // 32 KB
    __shared__ float vec[4][192];      // per-wave: ap | an | x
    int tid = threadIdx.x;
    for (int idx = tid; idx < 128 * 64; idx += 256) {
        int j = idx >> 6, c = idx & 63;
        W[idx] = (c < 32) ? W1p[j * 32 + c] : W1n[j * 32 + c - 32];
    }
    int wave = tid >> 6, lane = tid & 63;
    int node = blockIdx.x * 4 + wave;
    int nc   = node < n ? node : n - 1;           // clamp; store is guarded
    float invp = 1.0f / fmaxf(cnt_p[nc], 1.0f);
    float invn = 1.0f / fmaxf(cnt_n[nc], 1.0f);
    float ap = agg_p[nc * 64 + lane] * invp;
    float an = agg_n[nc * 64 + lane] * invn;
    float xi = x[nc * 64 + lane];
    vec[wave][lane]       = ap;
    vec[wave][64 + lane]  = an;
    vec[wave][128 + lane] = xi;
    __syncthreads();

    float acc = (lane < 32) ? b1p[lane] : b1n[lane - 32];
    const float* v = vec[wave];
    int abase = (lane < 32) ? 0 : 64;             // ap for pos half, an for neg half
    #pragma unroll 8
    for (int j = 0; j < 64; ++j)
        acc = fmaf(v[abase + j], W[j * 64 + lane], acc);
    #pragma unroll 8
    for (int j = 0; j < 64; ++j)
        acc = fmaf(v[128 + j], W[(64 + j) * 64 + lane], acc);
    if (node < n) z[node * 64 + lane] = tanhf(acc);
}

__global__ void __launch_bounds__(256) layer2_k(
    const float* __restrict__ zin,
    const float* __restrict__ agg_p, const float* __restrict__ agg_n,
    const float* __restrict__ cnt_p, const float* __restrict__ cnt_n,
    const float* __restrict__ W2p, const float* __restrict__ b2p,
    const float* __restrict__ W2n, const float* __restrict__ b2n,
    float* __restrict__ out, int n)
{
    __shared__ float W[96 * 64];       // 24 KB
    __shared__ float vec[4][192];      // per-wave: Ap | An | z
    int tid = threadIdx.x;
    for (int idx = tid; idx < 96 * 64; idx += 256) {
        int j = idx >> 6, c = idx & 63;
        W[idx] = (c < 32) ? W2p[j * 32 + c] : W2n[j * 32 + c - 32];
    }
    int wave = tid >> 6, lane = tid & 63;
    int node = blockIdx.x * 4 + wave;
    int nc   = node < n ? node : n - 1;
    float invp = 1.0f / fmaxf(cnt_p[nc], 1.0f);
    float invn = 1.0f / fmaxf(cnt_n[nc], 1.0f);
    float ap = agg_p[nc * 64 + lane] * invp;
    float an = agg_n[nc * 64 + lane] * invn;
    float zi = zin[nc * 64 + lane];
    vec[wave][lane]       = ap;
    vec[wave][64 + lane]  = an;
    vec[wave][128 + lane] = zi;
    __syncthreads();

    float acc = (lane < 32) ? b2p[lane] : b2n[lane - 32];
    const float* v = vec[wave];
    // out_p (lane<32): [Ap[0:32],  An[32:64], z[0:32] ]
    // out_n (lane>=32):[Ap[32:64], An[0:32],  z[32:64]]
    int o1 = (lane < 32) ? 0 : 32;
    int o2 = (lane < 32) ? 32 : 0;
    int o3 = (lane < 32) ? 0 : 32;
    #pragma unroll 8
    for (int j = 0; j < 32; ++j) {
        acc = fmaf(v[o1 + j],        W[j * 64 + lane],        acc);
        acc = fmaf(v[64 + o2 + j],   W[(32 + j) * 64 + lane], acc);
        acc = fmaf(v[128 + o3 + j],  W[(64 + j) * 64 + lane], acc);
    }
    if (node < n) out[node * 64 + lane] = tanhf(acc);
}

extern "C" void kernel_launch(void* const* d_in, const int* in_sizes, int n_in,
                              void* d_out, int out_size, void* d_ws, size_t ws_size,
                              hipStream_t stream)
{
    const float* x   = (const float*)d_in[0];
    const float* W1p = (const float*)d_in[1];
    const float* b1p = (const float*)d_in[2];
    const float* W1n = (const float*)d_in[3];
    const float* b1n = (const float*)d_in[4];
    const float* W2p = (const float*)d_in[5];
    const float* b2p = (const float*)d_in[6];
    const float* W2n = (const float*)d_in[7];
    const float* b2n = (const float*)d_in[8];
    const int*   pos = (const int*)d_in[9];
    const int*   neg = (const int*)d_in[10];

    int n = in_sizes[0] / 64;       // 100000
    int E = in_sizes[9] / 2;        // 1250000

    // workspace layout (floats): agg_p[n*64] agg_n[n*64] cnt_p[n] cnt_n[n] z[n*64]
    float* agg_p = (float*)d_ws;
    float* agg_n = agg_p + (size_t)n * 64;
    float* cnt_p = agg_n + (size_t)n * 64;
    float* cnt_n = cnt_p + n;
    float* z     = cnt_n + n;

    // zero agg_p, agg_n, cnt_p, cnt_n (contiguous prefix)
    hipMemsetAsync(d_ws, 0, ((size_t)n * 128 + 2 * (size_t)n) * sizeof(float), stream);

    int sblocks = (2 * E * 64 + 255) / 256;
    int lblocks = (n + 3) / 4;

    scatter2<<<sblocks, 256, 0, stream>>>(x, pos, neg, agg_p, agg_n, cnt_p, cnt_n, E, 1);
    layer1_k<<<lblocks, 256, 0, stream>>>(x, agg_p, agg_n, cnt_p, cnt_n,
                                          W1p, b1p, W1n, b1n, z, n);
    // re-zero aggregation buffers only (counts are reused for layer 2)
    hipMemsetAsync(agg_p, 0, (size_t)n * 128 * sizeof(float), stream);
    scatter2<<<sblocks, 256, 0, stream>>>(z, pos, neg, agg_p, agg_n, cnt_p, cnt_n, E, 0);
    layer2_k<<<lblocks, 256, 0, stream>>>(z, agg_p, agg_n, cnt_p, cnt_n,
                                          W2p, b2p, W2n, b2n, (float*)d_out, n);
}

// Round 2
// 787.860 us; speedup vs baseline: 1.9114x; 1.9114x over previous
//
#include <hip/hip_runtime.h>
#include <math.h>

// ---------------------------------------------------------------------------
// SGCN forward, fp32 — pull-based (CSR) aggregation fused with dense layers.
//
// Round-1 post-mortem: push-scatter was atomic-throughput-bound (243G f32
// atomics/s ~ 80% of TCC ceiling; WRITE_SIZE 703MB = L2 thrash of agg bufs).
// Round-2: build CSR per call (2.5M int atomics, 64x fewer), then pull:
// each node-wave accumulates its in-neighbors in registers. No f32 atomics,
// no agg buffers, aggregation fused directly into the dense layer kernels.
//
// Combined CSR over 2n segments: segments [0,n) = pos rows, [n,2n) = neg
// rows; col[] has pos edges in [0,E) and neg edges in [E,2E) automatically.
// Fill uses the in-place cursor trick: after fill, cur[i] = row_end(i),
// row_start(i) = (i==0 ? 0 : cur[i-1]).
// ---------------------------------------------------------------------------

__global__ void __launch_bounds__(256) hist_k(
    const int* __restrict__ pos, const int* __restrict__ neg,
    int* __restrict__ deg, int E, int n)
{
    int e = blockIdx.x * 256 + threadIdx.x;
    if (e < E)            atomicAdd(&deg[pos[E + e]], 1);
    else if (e < 2 * E)   atomicAdd(&deg[n + neg[E + (e - E)]], 1);
}

// Per-256-block exclusive scan; block totals to bsum.
__global__ void __launch_bounds__(256) scan1_k(
    const int* __restrict__ deg, int* __restrict__ cur,
    int* __restrict__ bsum, int n2)
{
    __shared__ int s[256];
    int tid = threadIdx.x;
    int i = blockIdx.x * 256 + tid;
    int v = (i < n2) ? deg[i] : 0;
    s[tid] = v;
    __syncthreads();
    for (int off = 1; off < 256; off <<= 1) {
        int t = (tid >= off) ? s[tid - off] : 0;
        __syncthreads();
        s[tid] += t;
        __syncthreads();
    }
    if (i < n2) cur[i] = s[tid] - v;            // exclusive within block
    if (tid == 255) bsum[blockIdx.x] = s[255];  // block total
}

// Single-block exclusive scan of block sums (nb <= 1024).
__global__ void __launch_bounds__(1024) scan2_k(int* __restrict__ bsum, int nb)
{
    __shared__ int s[1024];
    int tid = threadIdx.x;
    int v = (tid < nb) ? bsum[tid] : 0;
    s[tid] = v;
    __syncthreads();
    for (int off = 1; off < 1024; off <<= 1) {
        int t = (tid >= off) ? s[tid - off] : 0;
        __syncthreads();
        s[tid] += t;
        __syncthreads();
    }
    if (tid < nb) bsum[tid] = s[tid] - v;       // exclusive
}

__global__ void __launch_bounds__(256) scan3_k(
    int* __restrict__ cur, const int* __restrict__ bsum, int n2)
{
    int i = blockIdx.x * 256 + threadIdx.x;
    if (i < n2) cur[i] += bsum[blockIdx.x];
}

__global__ void __launch_bounds__(256) fill_k(
    const int* __restrict__ pos, const int* __restrict__ neg,
    int* __restrict__ cur, int* __restrict__ col, int E, int n)
{
    int e = blockIdx.x * 256 + threadIdx.x;
    int src, node;
    if (e < E)          { src = pos[e]; node = pos[E + e]; }
    else if (e < 2 * E) { int f = e - E; src = neg[f]; node = n + neg[E + f]; }
    else return;
    int slot = atomicAdd(&cur[node], 1);
    col[slot] = src;
}

// ---------------------------------------------------------------------------
// Fused pull + dense layers. One wave per node (grid-stride), lane = feature.
// Lanes 0..31 compute the pos-path output column, 32..63 the neg-path.
// W staged in LDS interleaved: W[j*64+c] = (c<32) ? Wp[j][c] : Wn[j][c-32].
// ---------------------------------------------------------------------------

__global__ void __launch_bounds__(256) layer1_pull(
    const float* __restrict__ x,
    const int* __restrict__ cur, const int* __restrict__ col,
    const float* __restrict__ W1p, const float* __restrict__ b1p,
    const float* __restrict__ W1n, const float* __restrict__ b1n,
    float* __restrict__ z, int n)
{
    __shared__ float W[128 * 64];      // 32 KB
    __shared__ float vec[4][192];      // per-wave private: ap | an | x
    int tid = threadIdx.x;
    for (int idx = tid; idx < 128 * 64; idx += 256) {
        int j = idx >> 6, c = idx & 63;
        W[idx] = (c < 32) ? W1p[j * 32 + c] : W1n[j * 32 + c - 32];
    }
    __syncthreads();
    int wave = tid >> 6, lane = tid & 63;
    int stride = gridDim.x * 4;
    for (int node = blockIdx.x * 4 + wave; node < n; node += stride) {
        int p0 = node ? cur[node - 1] : 0;
        int p1 = cur[node];
        int q0 = cur[n + node - 1];     // node==0 -> cur[n-1] == E (total pos)
        int q1 = cur[n + node];
        float accp = 0.f, accn = 0.f;
        #pragma unroll 4
        for (int i = p0; i < p1; ++i) { int s = col[i]; accp += x[s * 64 + lane]; }
        #pragma unroll 4
        for (int i = q0; i < q1; ++i) { int s = col[i]; accn += x[s * 64 + lane]; }
        float ap = accp / (float)max(p1 - p0, 1);
        float an = accn / (float)max(q1 - q0, 1);
        float xi = x[(size_t)node * 64 + lane];
        vec[wave][lane]       = ap;
        vec[wave][64 + lane]  = an;
        vec[wave][128 + lane] = xi;
        __builtin_amdgcn_wave_barrier();   // wave-private LDS; lockstep + may-alias ordering
        float acc = (lane < 32) ? b1p[lane] : b1n[lane - 32];
        const float* v = vec[wave];
        int abase = (lane < 32) ? 0 : 64;
        #pragma unroll 8
        for (int j = 0; j < 64; ++j)
            acc = fmaf(v[abase + j], W[j * 64 + lane], acc);
        #pragma unroll 8
        for (int j = 0; j < 64; ++j)
            acc = fmaf(v[128 + j], W[(64 + j) * 64 + lane], acc);
        z[(size_t)node * 64 + lane] = tanhf(acc);
        __builtin_amdgcn_wave_barrier();
    }
}

__global__ void __launch_bounds__(256) layer2_pull(
    const float* __restrict__ zin,
    const int* __restrict__ cur, const int* __restrict__ col,
    const float* __restrict__ W2p, const float* __restrict__ b2p,
    const float* __restrict__ W2n, const float* __restrict__ b2n,
    float* __restrict__ out, int n)
{
    __shared__ float W[96 * 64];       // 24 KB
    __shared__ float vec[4][192];      // per-wave private: Ap | An | z
    int tid = threadIdx.x;
    for (int idx = tid; idx < 96 * 64; idx += 256) {
        int j = idx >> 6, c = idx & 63;
        W[idx] = (c < 32) ? W2p[j * 32 + c] : W2n[j * 32 + c - 32];
    }
    __syncthreads();
    int wave = tid >> 6, lane = tid & 63;
    int stride = gridDim.x * 4;
    for (int node = blockIdx.x * 4 + wave; node < n; node += stride) {
        int p0 = node ? cur[node - 1] : 0;
        int p1 = cur[node];
        int q0 = cur[n + node - 1];
        int q1 = cur[n + node];
        float accp = 0.f, accn = 0.f;
        #pragma unroll 4
        for (int i = p0; i < p1; ++i) { int s = col[i]; accp += zin[s * 64 + lane]; }
        #pragma unroll 4
        for (int i = q0; i < q1; ++i) { int s = col[i]; accn += zin[s * 64 + lane]; }
        float ap = accp / (float)max(p1 - p0, 1);
        float an = accn / (float)max(q1 - q0, 1);
        float zi = zin[(size_t)node * 64 + lane];
        vec[wave][lane]       = ap;
        vec[wave][64 + lane]  = an;
        vec[wave][128 + lane] = zi;
        __builtin_amdgcn_wave_barrier();
        float acc = (lane < 32) ? b2p[lane] : b2n[lane - 32];
        const float* v = vec[wave];
        // out_p (lane<32): [Ap[0:32],  An[32:64], z[0:32] ]
        // out_n (lane>=32):[Ap[32:64], An[0:32],  z[32:64]]
        int o1 = (lane < 32) ? 0 : 32;
        int o2 = (lane < 32) ? 32 : 0;
        int o3 = (lane < 32) ? 0 : 32;
        #pragma unroll 8
        for (int j = 0; j < 32; ++j) {
            acc = fmaf(v[o1 + j],       W[j * 64 + lane],        acc);
            acc = fmaf(v[64 + o2 + j],  W[(32 + j) * 64 + lane], acc);
            acc = fmaf(v[128 + o3 + j], W[(64 + j) * 64 + lane], acc);
        }
        out[(size_t)node * 64 + lane] = tanhf(acc);
        __builtin_amdgcn_wave_barrier();
    }
}

extern "C" void kernel_launch(void* const* d_in, const int* in_sizes, int n_in,
                              void* d_out, int out_size, void* d_ws, size_t ws_size,
                              hipStream_t stream)
{
    const float* x   = (const float*)d_in[0];
    const float* W1p = (const float*)d_in[1];
    const float* b1p = (const float*)d_in[2];
    const float* W1n = (const float*)d_in[3];
    const float* b1n = (const float*)d_in[4];
    const float* W2p = (const float*)d_in[5];
    const float* b2p = (const float*)d_in[6];
    const float* W2n = (const float*)d_in[7];
    const float* b2n = (const float*)d_in[8];
    const int*   pos = (const int*)d_in[9];
    const int*   neg = (const int*)d_in[10];

    int n = in_sizes[0] / 64;       // 100000
    int E = in_sizes[9] / 2;        // 1250000
    int n2 = 2 * n;

    // workspace layout (ints/floats, all 4-byte):
    //   deg[2n] | cur[2n] | bsum[1024] | col[2E] | z[n*64]
    int*   deg  = (int*)d_ws;
    int*   cur  = deg + n2;
    int*   bsum = cur + n2;
    int*   col  = bsum + 1024;
    float* z    = (float*)(col + 2 * (size_t)E);

    hipMemsetAsync(deg, 0, (size_t)n2 * sizeof(int), stream);

    int eblocks = (2 * E + 255) / 256;
    int sblocks = (n2 + 255) / 256;          // 782 for n=100000

    hist_k <<<eblocks, 256, 0, stream>>>(pos, neg, deg, E, n);
    scan1_k<<<sblocks, 256, 0, stream>>>(deg, cur, bsum, n2);
    scan2_k<<<1, 1024, 0, stream>>>(bsum, sblocks);
    scan3_k<<<sblocks, 256, 0, stream>>>(cur, bsum, n2);
    fill_k <<<eblocks, 256, 0, stream>>>(pos, neg, cur, col, E, n);

    int lblocks = 2500;   // x4 waves = 10000 node-waves, 10 nodes each (n=100000)
    layer1_pull<<<lblocks, 256, 0, stream>>>(x, cur, col, W1p, b1p, W1n, b1n, z, n);
    layer2_pull<<<lblocks, 256, 0, stream>>>(z, cur, col, W2p, b2p, W2n, b2n,
                                             (float*)d_out, n);
}

// Round 3
// 601.725 us; speedup vs baseline: 2.5027x; 1.3093x over previous
//
#include <hip/hip_runtime.h>
#include <math.h>

// ---------------------------------------------------------------------------
// SGCN forward, fp32 — CSR pull aggregation fused with dense layers.
//
// R3 changes (layer kernels only):
//  * W staged in LDS as RNE-rounded bf16 PAIRS (uint32) -> layer1 LDS
//    35.8KB -> 19.4KB -> 8 blocks/CU (32 waves, was 16). Error budget:
//    |dW|/|W| <= 2^-9 over 128-term dots ~ +8e-4 absmax (thresh 1.1e-2).
//  * float4 gather: 16 lanes cover a 64-f row, 4 lane-groups process 4
//    edges/iteration; xor-shuffle reduction. ~8 wave-loads/node vs 25.
//  * dense phase: vec read as float4 broadcasts (b128), W as packed b64;
//    64 LDS instrs/node vs 256.
// ---------------------------------------------------------------------------

__device__ inline unsigned bfpack(float lo, float hi) {
    unsigned a = __float_as_uint(lo), b = __float_as_uint(hi);
    a += 0x7fffu + ((a >> 16) & 1u);          // RNE to bf16
    b += 0x7fffu + ((b >> 16) & 1u);
    return (a >> 16) | (b & 0xffff0000u);
}
__device__ inline float bflo(unsigned p) { return __uint_as_float(p << 16); }
__device__ inline float bfhi(unsigned p) { return __uint_as_float(p & 0xffff0000u); }

__device__ inline float4 shfl_xor4(float4 v, int m) {
    float4 r;
    r.x = __shfl_xor(v.x, m); r.y = __shfl_xor(v.y, m);
    r.z = __shfl_xor(v.z, m); r.w = __shfl_xor(v.w, m);
    return r;
}

// ------------------------------- CSR build ---------------------------------

__global__ void __launch_bounds__(256) hist_k(
    const int* __restrict__ pos, const int* __restrict__ neg,
    int* __restrict__ deg, int E, int n)
{
    int e = blockIdx.x * 256 + threadIdx.x;
    if (e < E)            atomicAdd(&deg[pos[E + e]], 1);
    else if (e < 2 * E)   atomicAdd(&deg[n + neg[E + (e - E)]], 1);
}

__global__ void __launch_bounds__(256) scan1_k(
    const int* __restrict__ deg, int* __restrict__ cur,
    int* __restrict__ bsum, int n2)
{
    __shared__ int s[256];
    int tid = threadIdx.x;
    int i = blockIdx.x * 256 + tid;
    int v = (i < n2) ? deg[i] : 0;
    s[tid] = v;
    __syncthreads();
    for (int off = 1; off < 256; off <<= 1) {
        int t = (tid >= off) ? s[tid - off] : 0;
        __syncthreads();
        s[tid] += t;
        __syncthreads();
    }
    if (i < n2) cur[i] = s[tid] - v;
    if (tid == 255) bsum[blockIdx.x] = s[255];
}

__global__ void __launch_bounds__(1024) scan2_k(int* __restrict__ bsum, int nb)
{
    __shared__ int s[1024];
    int tid = threadIdx.x;
    int v = (tid < nb) ? bsum[tid] : 0;
    s[tid] = v;
    __syncthreads();
    for (int off = 1; off < 1024; off <<= 1) {
        int t = (tid >= off) ? s[tid - off] : 0;
        __syncthreads();
        s[tid] += t;
        __syncthreads();
    }
    if (tid < nb) bsum[tid] = s[tid] - v;
}

__global__ void __launch_bounds__(256) scan3_k(
    int* __restrict__ cur, const int* __restrict__ bsum, int n2)
{
    int i = blockIdx.x * 256 + threadIdx.x;
    if (i < n2) cur[i] += bsum[blockIdx.x];
}

__global__ void __launch_bounds__(256) fill_k(
    const int* __restrict__ pos, const int* __restrict__ neg,
    int* __restrict__ cur, int* __restrict__ col, int E, int n)
{
    int e = blockIdx.x * 256 + threadIdx.x;
    int src, node;
    if (e < E)          { src = pos[e]; node = pos[E + e]; }
    else if (e < 2 * E) { int f = e - E; src = neg[f]; node = n + neg[E + f]; }
    else return;
    int slot = atomicAdd(&cur[node], 1);
    col[slot] = src;
}

// ------------------------- fused pull + dense layers ------------------------
// One wave per node (grid-stride over nodes). Gather: lane = 16g+f, group g
// handles edge p0+4*it+g, f indexes a float4 of the 64-f row. Dense: lane c
// computes output column c (c<32 pos path, c>=32 neg path).

__global__ void __launch_bounds__(256, 8) layer1_pull(
    const float* __restrict__ x,
    const int* __restrict__ cur, const int* __restrict__ col,
    const float* __restrict__ W1p, const float* __restrict__ b1p,
    const float* __restrict__ W1n, const float* __restrict__ b1n,
    float* __restrict__ z, int n)
{
    // Wq[j4*128 + 2c + k] packs W rows 4j4+2k (lo), 4j4+2k+1 (hi), column c
    // (c<32 -> W1p col c, else W1n col c-32). j = 0..127 over [a | x].
    __shared__ unsigned Wq[32 * 128];     // 16 KB
    __shared__ float4 vec4s[4][48];       // per-wave: ap(16) | an(16) | xi(16)
    int tid = threadIdx.x;
    for (int idx = tid; idx < 32 * 128; idx += 256) {
        int j4 = idx >> 7, r = idx & 127, c = r >> 1, k = r & 1;
        int j = 4 * j4 + 2 * k;
        int colw = c & 31;
        const float* Ws = (c < 32) ? W1p : W1n;
        Wq[idx] = bfpack(Ws[j * 32 + colw], Ws[(j + 1) * 32 + colw]);
    }
    __syncthreads();

    const float4* x4 = (const float4*)x;
    int wave = tid >> 6, lane = tid & 63;
    int g = lane >> 4, f = lane & 15;
    int c = lane;
    float bb = (c < 32) ? b1p[c] : b1n[c - 32];
    int ab4 = (c < 32) ? 0 : 16;
    float4* vec = vec4s[wave];

    int stride = gridDim.x * 4;
    for (int node = blockIdx.x * 4 + wave; node < n; node += stride) {
        int p0 = node ? cur[node - 1] : 0;
        int p1 = cur[node];
        int q0 = cur[n + node - 1];
        int q1 = cur[n + node];

        float4 a4 = {0.f, 0.f, 0.f, 0.f}, b4 = {0.f, 0.f, 0.f, 0.f};
        #pragma unroll 2
        for (int it = p0 + g; it < p1; it += 4) {
            int s = col[it];
            float4 t = x4[(size_t)s * 16 + f];
            a4.x += t.x; a4.y += t.y; a4.z += t.z; a4.w += t.w;
        }
        #pragma unroll 2
        for (int it = q0 + g; it < q1; it += 4) {
            int s = col[it];
            float4 t = x4[(size_t)s * 16 + f];
            b4.x += t.x; b4.y += t.y; b4.z += t.z; b4.w += t.w;
        }
        float4 t;
        t = shfl_xor4(a4, 16); a4.x += t.x; a4.y += t.y; a4.z += t.z; a4.w += t.w;
        t = shfl_xor4(a4, 32); a4.x += t.x; a4.y += t.y; a4.z += t.z; a4.w += t.w;
        t = shfl_xor4(b4, 16); b4.x += t.x; b4.y += t.y; b4.z += t.z; b4.w += t.w;
        t = shfl_xor4(b4, 32); b4.x += t.x; b4.y += t.y; b4.z += t.z; b4.w += t.w;
        float rp = 1.0f / (float)max(p1 - p0, 1);
        float rq = 1.0f / (float)max(q1 - q0, 1);
        a4.x *= rp; a4.y *= rp; a4.z *= rp; a4.w *= rp;
        b4.x *= rq; b4.y *= rq; b4.z *= rq; b4.w *= rq;
        float4 xi4 = x4[(size_t)node * 16 + f];
        float4 sv = (g == 0) ? a4 : (g == 1) ? b4 : xi4;
        if (g < 3) vec[g * 16 + f] = sv;
        __builtin_amdgcn_wave_barrier();

        float acc = bb;
        #pragma unroll 4
        for (int j4 = 0; j4 < 16; ++j4) {        // a-part (ap or an by half)
            float4 v4 = vec[ab4 + j4];
            unsigned w0 = Wq[j4 * 128 + 2 * c];
            unsigned w1 = Wq[j4 * 128 + 2 * c + 1];
            acc = fmaf(v4.x, bflo(w0), acc);
            acc = fmaf(v4.y, bfhi(w0), acc);
            acc = fmaf(v4.z, bflo(w1), acc);
            acc = fmaf(v4.w, bfhi(w1), acc);
        }
        #pragma unroll 4
        for (int j4 = 0; j4 < 16; ++j4) {        // x-part (shared)
            float4 v4 = vec[32 + j4];
            unsigned w0 = Wq[(16 + j4) * 128 + 2 * c];
            unsigned w1 = Wq[(16 + j4) * 128 + 2 * c + 1];
            acc = fmaf(v4.x, bflo(w0), acc);
            acc = fmaf(v4.y, bfhi(w0), acc);
            acc = fmaf(v4.z, bflo(w1), acc);
            acc = fmaf(v4.w, bfhi(w1), acc);
        }
        z[(size_t)node * 64 + c] = tanhf(acc);
        __builtin_amdgcn_wave_barrier();
    }
}

__global__ void __launch_bounds__(256, 8) layer2_pull(
    const float* __restrict__ zin,
    const int* __restrict__ cur, const int* __restrict__ col,
    const float* __restrict__ W2p, const float* __restrict__ b2p,
    const float* __restrict__ W2n, const float* __restrict__ b2n,
    float* __restrict__ out, int n)
{
    __shared__ unsigned Wq[24 * 128];     // 12 KB, j = 0..95 over [Ap|An|z] order
    __shared__ float4 vec4s[4][48];       // per-wave: Ap(16) | An(16) | z(16)
    int tid = threadIdx.x;
    for (int idx = tid; idx < 24 * 128; idx += 256) {
        int j4 = idx >> 7, r = idx & 127, c = r >> 1, k = r & 1;
        int j = 4 * j4 + 2 * k;
        int colw = c & 31;
        const float* Ws = (c < 32) ? W2p : W2n;
        Wq[idx] = bfpack(Ws[j * 32 + colw], Ws[(j + 1) * 32 + colw]);
    }
    __syncthreads();

    const float4* z4 = (const float4*)zin;
    int wave = tid >> 6, lane = tid & 63;
    int g = lane >> 4, f = lane & 15;
    int c = lane;
    float bb = (c < 32) ? b2p[c] : b2n[c - 32];
    // v segments (in vec4 units): pos half: Ap[0:32]=0..7, An[32:64]=24..31,
    // z[0:32]=32..39 ; neg half: Ap[32:64]=8..15, An[0:32]=16..23, z[32:64]=40..47
    int s1 = (c < 32) ? 0 : 8;
    int s2 = (c < 32) ? 24 : 16;
    int s3 = (c < 32) ? 32 : 40;
    float4* vec = vec4s[wave];

    int stride = gridDim.x * 4;
    for (int node = blockIdx.x * 4 + wave; node < n; node += stride) {
        int p0 = node ? cur[node - 1] : 0;
        int p1 = cur[node];
        int q0 = cur[n + node - 1];
        int q1 = cur[n + node];

        float4 a4 = {0.f, 0.f, 0.f, 0.f}, b4 = {0.f, 0.f, 0.f, 0.f};
        #pragma unroll 2
        for (int it = p0 + g; it < p1; it += 4) {
            int s = col[it];
            float4 t = z4[(size_t)s * 16 + f];
            a4.x += t.x; a4.y += t.y; a4.z += t.z; a4.w += t.w;
        }
        #pragma unroll 2
        for (int it = q0 + g; it < q1; it += 4) {
            int s = col[it];
            float4 t = z4[(size_t)s * 16 + f];
            b4.x += t.x; b4.y += t.y; b4.z += t.z; b4.w += t.w;
        }
        float4 t;
        t = shfl_xor4(a4, 16); a4.x += t.x; a4.y += t.y; a4.z += t.z; a4.w += t.w;
        t = shfl_xor4(a4, 32); a4.x += t.x; a4.y += t.y; a4.z += t.z; a4.w += t.w;
        t = shfl_xor4(b4, 16); b4.x += t.x; b4.y += t.y; b4.z += t.z; b4.w += t.w;
        t = shfl_xor4(b4, 32); b4.x += t.x; b4.y += t.y; b4.z += t.z; b4.w += t.w;
        float rp = 1.0f / (float)max(p1 - p0, 1);
        float rq = 1.0f / (float)max(q1 - q0, 1);
        a4.x *= rp; a4.y *= rp; a4.z *= rp; a4.w *= rp;
        b4.x *= rq; b4.y *= rq; b4.z *= rq; b4.w *= rq;
        float4 zi4 = z4[(size_t)node * 16 + f];
        float4 sv = (g == 0) ? a4 : (g == 1) ? b4 : zi4;
        if (g < 3) vec[g * 16 + f] = sv;
        __builtin_amdgcn_wave_barrier();

        float acc = bb;
        #pragma unroll 4
        for (int j4 = 0; j4 < 8; ++j4) {         // Ap segment
            float4 v4 = vec[s1 + j4];
            unsigned w0 = Wq[j4 * 128 + 2 * c];
            unsigned w1 = Wq[j4 * 128 + 2 * c + 1];
            acc = fmaf(v4.x, bflo(w0), acc);
            acc = fmaf(v4.y, bfhi(w0), acc);
            acc = fmaf(v4.z, bflo(w1), acc);
            acc = fmaf(v4.w, bfhi(w1), acc);
        }
        #pragma unroll 4
        for (int j4 = 0; j4 < 8; ++j4) {         // An segment
            float4 v4 = vec[s2 + j4];
            unsigned w0 = Wq[(8 + j4) * 128 + 2 * c];
            unsigned w1 = Wq[(8 + j4) * 128 + 2 * c + 1];
            acc = fmaf(v4.x, bflo(w0), acc);
            acc = fmaf(v4.y, bfhi(w0), acc);
            acc = fmaf(v4.z, bflo(w1), acc);
            acc = fmaf(v4.w, bfhi(w1), acc);
        }
        #pragma unroll 4
        for (int j4 = 0; j4 < 8; ++j4) {         // z segment
            float4 v4 = vec[s3 + j4];
            unsigned w0 = Wq[(16 + j4) * 128 + 2 * c];
            unsigned w1 = Wq[(16 + j4) * 128 + 2 * c + 1];
            acc = fmaf(v4.x, bflo(w0), acc);
            acc = fmaf(v4.y, bfhi(w0), acc);
            acc = fmaf(v4.z, bflo(w1), acc);
            acc = fmaf(v4.w, bfhi(w1), acc);
        }
        out[(size_t)node * 64 + c] = tanhf(acc);
        __builtin_amdgcn_wave_barrier();
    }
}

extern "C" void kernel_launch(void* const* d_in, const int* in_sizes, int n_in,
                              void* d_out, int out_size, void* d_ws, size_t ws_size,
                              hipStream_t stream)
{
    const float* x   = (const float*)d_in[0];
    const float* W1p = (const float*)d_in[1];
    const float* b1p = (const float*)d_in[2];
    const float* W1n = (const float*)d_in[3];
    const float* b1n = (const float*)d_in[4];
    const float* W2p = (const float*)d_in[5];
    const float* b2p = (const float*)d_in[6];
    const float* W2n = (const float*)d_in[7];
    const float* b2n = (const float*)d_in[8];
    const int*   pos = (const int*)d_in[9];
    const int*   neg = (const int*)d_in[10];

    int n = in_sizes[0] / 64;       // 100000
    int E = in_sizes[9] / 2;        // 1250000
    int n2 = 2 * n;

    // workspace: deg[2n] | cur[2n] | bsum[1024] | col[2E] | z[n*64]
    int*   deg  = (int*)d_ws;
    int*   cur  = deg + n2;
    int*   bsum = cur + n2;
    int*   col  = bsum + 1024;
    float* z    = (float*)(col + 2 * (size_t)E);

    hipMemsetAsync(deg, 0, (size_t)n2 * sizeof(int), stream);

    int eblocks = (2 * E + 255) / 256;
    int sblocks = (n2 + 255) / 256;

    hist_k <<<eblocks, 256, 0, stream>>>(pos, neg, deg, E, n);
    scan1_k<<<sblocks, 256, 0, stream>>>(deg, cur, bsum, n2);
    scan2_k<<<1, 1024, 0, stream>>>(bsum, sblocks);
    scan3_k<<<sblocks, 256, 0, stream>>>(cur, bsum, n2);
    fill_k <<<eblocks, 256, 0, stream>>>(pos, neg, cur, col, E, n);

    int lblocks = 2048;   // 8 blocks/CU resident; grid-stride over nodes
    layer1_pull<<<lblocks, 256, 0, stream>>>(x, cur, col, W1p, b1p, W1n, b1n, z, n);
    layer2_pull<<<lblocks, 256, 0, stream>>>(z, cur, col, W2p, b2p, W2n, b2n,
                                             (float*)d_out, n);
}

// Round 4
// 513.164 us; speedup vs baseline: 2.9346x; 1.1726x over previous
//
#include <hip/hip_runtime.h>
#include <math.h>

// ---------------------------------------------------------------------------
// SGCN forward, fp32 — CSR pull aggregation fused with dense layers.
//
// R4 change: fill_k was write-amplification-bound (172MB WRITE_SIZE for a
// 10MB col[] array: random 4B stores -> ~1 line writeback per 2 stores).
// New fill partitions the dst space into 8 ranges, one per XCD (blockIdx&7
// exploits round-robin block->XCD dispatch). Each XCD then writes a dense
// private 1.25MB col region (~16 stores/line), amp -> ~1. The 8x re-stream
// of the 10MB dst list is sequential + L3-resident.
// ---------------------------------------------------------------------------

__device__ inline unsigned bfpack(float lo, float hi) {
    unsigned a = __float_as_uint(lo), b = __float_as_uint(hi);
    a += 0x7fffu + ((a >> 16) & 1u);          // RNE to bf16
    b += 0x7fffu + ((b >> 16) & 1u);
    return (a >> 16) | (b & 0xffff0000u);
}
__device__ inline float bflo(unsigned p) { return __uint_as_float(p << 16); }
__device__ inline float bfhi(unsigned p) { return __uint_as_float(p & 0xffff0000u); }

__device__ inline float4 shfl_xor4(float4 v, int m) {
    float4 r;
    r.x = __shfl_xor(v.x, m); r.y = __shfl_xor(v.y, m);
    r.z = __shfl_xor(v.z, m); r.w = __shfl_xor(v.w, m);
    return r;
}

// ------------------------------- CSR build ---------------------------------

__global__ void __launch_bounds__(256) hist_k(
    const int* __restrict__ pos, const int* __restrict__ neg,
    int* __restrict__ deg, int E, int n)
{
    int e = blockIdx.x * 256 + threadIdx.x;
    if (e < E)            atomicAdd(&deg[pos[E + e]], 1);
    else if (e < 2 * E)   atomicAdd(&deg[n + neg[E + (e - E)]], 1);
}

__global__ void __launch_bounds__(256) scan1_k(
    const int* __restrict__ deg, int* __restrict__ cur,
    int* __restrict__ bsum, int n2)
{
    __shared__ int s[256];
    int tid = threadIdx.x;
    int i = blockIdx.x * 256 + tid;
    int v = (i < n2) ? deg[i] : 0;
    s[tid] = v;
    __syncthreads();
    for (int off = 1; off < 256; off <<= 1) {
        int t = (tid >= off) ? s[tid - off] : 0;
        __syncthreads();
        s[tid] += t;
        __syncthreads();
    }
    if (i < n2) cur[i] = s[tid] - v;
    if (tid == 255) bsum[blockIdx.x] = s[255];
}

__global__ void __launch_bounds__(1024) scan2_k(int* __restrict__ bsum, int nb)
{
    __shared__ int s[1024];
    int tid = threadIdx.x;
    int v = (tid < nb) ? bsum[tid] : 0;
    s[tid] = v;
    __syncthreads();
    for (int off = 1; off < 1024; off <<= 1) {
        int t = (tid >= off) ? s[tid - off] : 0;
        __syncthreads();
        s[tid] += t;
        __syncthreads();
    }
    if (tid < nb) bsum[tid] = s[tid] - v;
}

__global__ void __launch_bounds__(256) scan3_k(
    int* __restrict__ cur, const int* __restrict__ bsum, int n2)
{
    int i = blockIdx.x * 256 + threadIdx.x;
    if (i < n2) cur[i] += bsum[blockIdx.x];
}

// XCD-partitioned fill: block b serves dst-partition (b & 7); streams the
// whole edge list and fills only edges whose dst falls in its 1/8 range.
__global__ void __launch_bounds__(256) fill_k(
    const int* __restrict__ pos, const int* __restrict__ neg,
    int* __restrict__ cur, int* __restrict__ col, int E, int n,
    int blocksPerPart)
{
    int part = blockIdx.x & 7;
    int wb   = blockIdx.x >> 3;
    int n2 = 2 * n;
    int lo = (int)(((long long)n2 * part) >> 3);
    int hi = (int)(((long long)n2 * (part + 1)) >> 3);
    int stride = blocksPerPart * 256;
    for (int e = wb * 256 + (int)threadIdx.x; e < 2 * E; e += stride) {
        int node;
        if (e < E) node = pos[E + e];
        else       node = n + neg[E + (e - E)];
        if (node >= lo && node < hi) {
            int src = (e < E) ? pos[e] : neg[e - E];
            int slot = atomicAdd(&cur[node], 1);
            col[slot] = src;
        }
    }
}

// ------------------------- fused pull + dense layers ------------------------
// One wave per node (grid-stride over nodes). Gather: lane = 16g+f, group g
// handles edge p0+4*it+g, f indexes a float4 of the 64-f row. Dense: lane c
// computes output column c (c<32 pos path, c>=32 neg path).

__global__ void __launch_bounds__(256, 8) layer1_pull(
    const float* __restrict__ x,
    const int* __restrict__ cur, const int* __restrict__ col,
    const float* __restrict__ W1p, const float* __restrict__ b1p,
    const float* __restrict__ W1n, const float* __restrict__ b1n,
    float* __restrict__ z, int n)
{
    // Wq[j4*128 + 2c + k] packs W rows 4j4+2k (lo), 4j4+2k+1 (hi), column c
    // (c<32 -> W1p col c, else W1n col c-32). j = 0..127 over [a | x].
    __shared__ unsigned Wq[32 * 128];     // 16 KB
    __shared__ float4 vec4s[4][48];       // per-wave: ap(16) | an(16) | xi(16)
    int tid = threadIdx.x;
    for (int idx = tid; idx < 32 * 128; idx += 256) {
        int j4 = idx >> 7, r = idx & 127, c = r >> 1, k = r & 1;
        int j = 4 * j4 + 2 * k;
        int colw = c & 31;
        const float* Ws = (c < 32) ? W1p : W1n;
        Wq[idx] = bfpack(Ws[j * 32 + colw], Ws[(j + 1) * 32 + colw]);
    }
    __syncthreads();

    const float4* x4 = (const float4*)x;
    int wave = tid >> 6, lane = tid & 63;
    int g = lane >> 4, f = lane & 15;
    int c = lane;
    float bb = (c < 32) ? b1p[c] : b1n[c - 32];
    int ab4 = (c < 32) ? 0 : 16;
    float4* vec = vec4s[wave];

    int stride = gridDim.x * 4;
    for (int node = blockIdx.x * 4 + wave; node < n; node += stride) {
        int p0 = node ? cur[node - 1] : 0;
        int p1 = cur[node];
        int q0 = cur[n + node - 1];
        int q1 = cur[n + node];

        float4 a4 = {0.f, 0.f, 0.f, 0.f}, b4 = {0.f, 0.f, 0.f, 0.f};
        #pragma unroll 2
        for (int it = p0 + g; it < p1; it += 4) {
            int s = col[it];
            float4 t = x4[(size_t)s * 16 + f];
            a4.x += t.x; a4.y += t.y; a4.z += t.z; a4.w += t.w;
        }
        #pragma unroll 2
        for (int it = q0 + g; it < q1; it += 4) {
            int s = col[it];
            float4 t = x4[(size_t)s * 16 + f];
            b4.x += t.x; b4.y += t.y; b4.z += t.z; b4.w += t.w;
        }
        float4 t;
        t = shfl_xor4(a4, 16); a4.x += t.x; a4.y += t.y; a4.z += t.z; a4.w += t.w;
        t = shfl_xor4(a4, 32); a4.x += t.x; a4.y += t.y; a4.z += t.z; a4.w += t.w;
        t = shfl_xor4(b4, 16); b4.x += t.x; b4.y += t.y; b4.z += t.z; b4.w += t.w;
        t = shfl_xor4(b4, 32); b4.x += t.x; b4.y += t.y; b4.z += t.z; b4.w += t.w;
        float rp = 1.0f / (float)max(p1 - p0, 1);
        float rq = 1.0f / (float)max(q1 - q0, 1);
        a4.x *= rp; a4.y *= rp; a4.z *= rp; a4.w *= rp;
        b4.x *= rq; b4.y *= rq; b4.z *= rq; b4.w *= rq;
        float4 xi4 = x4[(size_t)node * 16 + f];
        float4 sv = (g == 0) ? a4 : (g == 1) ? b4 : xi4;
        if (g < 3) vec[g * 16 + f] = sv;
        __builtin_amdgcn_wave_barrier();

        float acc = bb;
        #pragma unroll 4
        for (int j4 = 0; j4 < 16; ++j4) {        // a-part (ap or an by half)
            float4 v4 = vec[ab4 + j4];
            unsigned w0 = Wq[j4 * 128 + 2 * c];
            unsigned w1 = Wq[j4 * 128 + 2 * c + 1];
            acc = fmaf(v4.x, bflo(w0), acc);
            acc = fmaf(v4.y, bfhi(w0), acc);
            acc = fmaf(v4.z, bflo(w1), acc);
            acc = fmaf(v4.w, bfhi(w1), acc);
        }
        #pragma unroll 4
        for (int j4 = 0; j4 < 16; ++j4) {        // x-part (shared)
            float4 v4 = vec[32 + j4];
            unsigned w0 = Wq[(16 + j4) * 128 + 2 * c];
            unsigned w1 = Wq[(16 + j4) * 128 + 2 * c + 1];
            acc = fmaf(v4.x, bflo(w0), acc);
            acc = fmaf(v4.y, bfhi(w0), acc);
            acc = fmaf(v4.z, bflo(w1), acc);
            acc = fmaf(v4.w, bfhi(w1), acc);
        }
        z[(size_t)node * 64 + c] = tanhf(acc);
        __builtin_amdgcn_wave_barrier();
    }
}

__global__ void __launch_bounds__(256, 8) layer2_pull(
    const float* __restrict__ zin,
    const int* __restrict__ cur, const int* __restrict__ col,
    const float* __restrict__ W2p, const float* __restrict__ b2p,
    const float* __restrict__ W2n, const float* __restrict__ b2n,
    float* __restrict__ out, int n)
{
    __shared__ unsigned Wq[24 * 128];     // 12 KB, j = 0..95 over [Ap|An|z] order
    __shared__ float4 vec4s[4][48];       // per-wave: Ap(16) | An(16) | z(16)
    int tid = threadIdx.x;
    for (int idx = tid; idx < 24 * 128; idx += 256) {
        int j4 = idx >> 7, r = idx & 127, c = r >> 1, k = r & 1;
        int j = 4 * j4 + 2 * k;
        int colw = c & 31;
        const float* Ws = (c < 32) ? W2p : W2n;
        Wq[idx] = bfpack(Ws[j * 32 + colw], Ws[(j + 1) * 32 + colw]);
    }
    __syncthreads();

    const float4* z4 = (const float4*)zin;
    int wave = tid >> 6, lane = tid & 63;
    int g = lane >> 4, f = lane & 15;
    int c = lane;
    float bb = (c < 32) ? b2p[c] : b2n[c - 32];
    // v segments (in vec4 units): pos half: Ap[0:32]=0..7, An[32:64]=24..31,
    // z[0:32]=32..39 ; neg half: Ap[32:64]=8..15, An[0:32]=16..23, z[32:64]=40..47
    int s1 = (c < 32) ? 0 : 8;
    int s2 = (c < 32) ? 24 : 16;
    int s3 = (c < 32) ? 32 : 40;
    float4* vec = vec4s[wave];

    int stride = gridDim.x * 4;
    for (int node = blockIdx.x * 4 + wave; node < n; node += stride) {
        int p0 = node ? cur[node - 1] : 0;
        int p1 = cur[node];
        int q0 = cur[n + node - 1];
        int q1 = cur[n + node];

        float4 a4 = {0.f, 0.f, 0.f, 0.f}, b4 = {0.f, 0.f, 0.f, 0.f};
        #pragma unroll 2
        for (int it = p0 + g; it < p1; it += 4) {
            int s = col[it];
            float4 t = z4[(size_t)s * 16 + f];
            a4.x += t.x; a4.y += t.y; a4.z += t.z; a4.w += t.w;
        }
        #pragma unroll 2
        for (int it = q0 + g; it < q1; it += 4) {
            int s = col[it];
            float4 t = z4[(size_t)s * 16 + f];
            b4.x += t.x; b4.y += t.y; b4.z += t.z; b4.w += t.w;
        }
        float4 t;
        t = shfl_xor4(a4, 16); a4.x += t.x; a4.y += t.y; a4.z += t.z; a4.w += t.w;
        t = shfl_xor4(a4, 32); a4.x += t.x; a4.y += t.y; a4.z += t.z; a4.w += t.w;
        t = shfl_xor4(b4, 16); b4.x += t.x; b4.y += t.y; b4.z += t.z; b4.w += t.w;
        t = shfl_xor4(b4, 32); b4.x += t.x; b4.y += t.y; b4.z += t.z; b4.w += t.w;
        float rp = 1.0f / (float)max(p1 - p0, 1);
        float rq = 1.0f / (float)max(q1 - q0, 1);
        a4.x *= rp; a4.y *= rp; a4.z *= rp; a4.w *= rp;
        b4.x *= rq; b4.y *= rq; b4.z *= rq; b4.w *= rq;
        float4 zi4 = z4[(size_t)node * 16 + f];
        float4 sv = (g == 0) ? a4 : (g == 1) ? b4 : zi4;
        if (g < 3) vec[g * 16 + f] = sv;
        __builtin_amdgcn_wave_barrier();

        float acc = bb;
        #pragma unroll 4
        for (int j4 = 0; j4 < 8; ++j4) {         // Ap segment
            float4 v4 = vec[s1 + j4];
            unsigned w0 = Wq[j4 * 128 + 2 * c];
            unsigned w1 = Wq[j4 * 128 + 2 * c + 1];
            acc = fmaf(v4.x, bflo(w0), acc);
            acc = fmaf(v4.y, bfhi(w0), acc);
            acc = fmaf(v4.z, bflo(w1), acc);
            acc = fmaf(v4.w, bfhi(w1), acc);
        }
        #pragma unroll 4
        for (int j4 = 0; j4 < 8; ++j4) {         // An segment
            float4 v4 = vec[s2 + j4];
            unsigned w0 = Wq[(8 + j4) * 128 + 2 * c];
            unsigned w1 = Wq[(8 + j4) * 128 + 2 * c + 1];
            acc = fmaf(v4.x, bflo(w0), acc);
            acc = fmaf(v4.y, bfhi(w0), acc);
            acc = fmaf(v4.z, bflo(w1), acc);
            acc = fmaf(v4.w, bfhi(w1), acc);
        }
        #pragma unroll 4
        for (int j4 = 0; j4 < 8; ++j4) {         // z segment
            float4 v4 = vec[s3 + j4];
            unsigned w0 = Wq[(16 + j4) * 128 + 2 * c];
            unsigned w1 = Wq[(16 + j4) * 128 + 2 * c + 1];
            acc = fmaf(v4.x, bflo(w0), acc);
            acc = fmaf(v4.y, bfhi(w0), acc);
            acc = fmaf(v4.z, bflo(w1), acc);
            acc = fmaf(v4.w, bfhi(w1), acc);
        }
        out[(size_t)node * 64 + c] = tanhf(acc);
        __builtin_amdgcn_wave_barrier();
    }
}

extern "C" void kernel_launch(void* const* d_in, const int* in_sizes, int n_in,
                              void* d_out, int out_size, void* d_ws, size_t ws_size,
                              hipStream_t stream)
{
    const float* x   = (const float*)d_in[0];
    const float* W1p = (const float*)d_in[1];
    const float* b1p = (const float*)d_in[2];
    const float* W1n = (const float*)d_in[3];
    const float* b1n = (const float*)d_in[4];
    const float* W2p = (const float*)d_in[5];
    const float* b2p = (const float*)d_in[6];
    const float* W2n = (const float*)d_in[7];
    const float* b2n = (const float*)d_in[8];
    const int*   pos = (const int*)d_in[9];
    const int*   neg = (const int*)d_in[10];

    int n = in_sizes[0] / 64;       // 100000
    int E = in_sizes[9] / 2;        // 1250000
    int n2 = 2 * n;

    // workspace: deg[2n] | cur[2n] | bsum[1024] | col[2E] | z[n*64]
    int*   deg  = (int*)d_ws;
    int*   cur  = deg + n2;
    int*   bsum = cur + n2;
    int*   col  = bsum + 1024;
    float* z    = (float*)(col + 2 * (size_t)E);

    hipMemsetAsync(deg, 0, (size_t)n2 * sizeof(int), stream);

    int eblocks = (2 * E + 255) / 256;
    int sblocks = (n2 + 255) / 256;

    hist_k <<<eblocks, 256, 0, stream>>>(pos, neg, deg, E, n);
    scan1_k<<<sblocks, 256, 0, stream>>>(deg, cur, bsum, n2);
    scan2_k<<<1, 1024, 0, stream>>>(bsum, sblocks);
    scan3_k<<<sblocks, 256, 0, stream>>>(cur, bsum, n2);

    int bpp = 128;                           // blocks per dst-partition
    fill_k <<<8 * bpp, 256, 0, stream>>>(pos, neg, cur, col, E, n, bpp);

    int lblocks = 2048;   // 8 blocks/CU resident; grid-stride over nodes
    layer1_pull<<<lblocks, 256, 0, stream>>>(x, cur, col, W1p, b1p, W1n, b1n, z, n);
    layer2_pull<<<lblocks, 256, 0, stream>>>(z, cur, col, W2p, b2p, W2n, b2n,
                                             (float*)d_out, n);
}